// Round 4
// baseline (786.140 us; speedup 1.0000x reference)
//
#include <hip/hip_runtime.h>
#include <hip/hip_bf16.h>

#define DD 128
#define HH 16
#define SCAN_B 1024
#define EPB 256        // CSR positions per block in edgenode_kernel
#define VT_STRIDE 132  // padded row stride (bf16) for vt tile

typedef __bf16 bf16x8 __attribute__((ext_vector_type(8)));
typedef float f32x4 __attribute__((ext_vector_type(4)));

// ---------------- LayerNorm: one wave per node ----------------
__global__ void ln_kernel(const float* __restrict__ x, const float* __restrict__ g,
                          const float* __restrict__ b, float* __restrict__ xn, int n_nodes) {
  int w = (blockIdx.x * blockDim.x + threadIdx.x) >> 6;
  int lane = threadIdx.x & 63;
  if (w >= n_nodes) return;
  const float* xr = x + (size_t)w * DD;
  float a0 = xr[lane], a1 = xr[lane + 64];
  float s = a0 + a1;
  #pragma unroll
  for (int o = 32; o > 0; o >>= 1) s += __shfl_down(s, o);
  s = __shfl(s, 0);
  float mu = s * (1.0f / DD);
  float d0 = a0 - mu, d1 = a1 - mu;
  float v = d0 * d0 + d1 * d1;
  #pragma unroll
  for (int o = 32; o > 0; o >>= 1) v += __shfl_down(v, o);
  v = __shfl(v, 0);
  float rstd = rsqrtf(v * (1.0f / DD) + 1e-5f);
  float* xo = xn + (size_t)w * DD;
  xo[lane]      = d0 * rstd * g[lane] + b[lane];
  xo[lane + 64] = d1 * rstd * g[lane + 64] + b[lane + 64];
}

// ---------------- xn @ [ia1_w | oa1_w] -> xw_a [N,32] ----------------
__global__ __launch_bounds__(256) void proj1_kernel(const float* __restrict__ xn,
    const float* __restrict__ ia1_w, const float* __restrict__ oa1_w,
    float* __restrict__ xw_a, int n_nodes) {
  __shared__ __align__(16) float wl[DD * 32];
  for (int i = threadIdx.x; i < DD * HH; i += 256) {
    int dd = i >> 4, jj = i & 15;
    wl[dd * 32 + jj]      = ia1_w[i];
    wl[dd * 32 + 16 + jj] = oa1_w[i];
  }
  __syncthreads();
  int t = blockIdx.x * blockDim.x + threadIdx.x;
  int n = t >> 5, j = t & 31;
  if (n >= n_nodes) return;
  const float* xr = xn + (size_t)n * DD;
  float acc = 0.f;
  #pragma unroll 8
  for (int d = 0; d < DD; ++d) acc = fmaf(xr[d], wl[d * 32 + j], acc);
  xw_a[(size_t)n * 32 + j] = acc;
}

// ---------------- degree histogram (int) ----------------
__global__ void degcnt_kernel(const int* __restrict__ dst, int* __restrict__ deg, int n_edges) {
  int e = blockIdx.x * blockDim.x + threadIdx.x;
  if (e < n_edges) atomicAdd(&deg[dst[e]], 1);
}

// ---------------- 3-kernel exclusive scan over deg -> rs ----------------
__global__ __launch_bounds__(SCAN_B) void scan1_kernel(const int* __restrict__ deg,
    int* __restrict__ rs, int* __restrict__ partials, int n_nodes) {
  __shared__ int sm[SCAN_B];
  int i = blockIdx.x * SCAN_B + threadIdx.x;
  int v = (i < n_nodes) ? deg[i] : 0;
  sm[threadIdx.x] = v;
  __syncthreads();
  for (int o = 1; o < SCAN_B; o <<= 1) {
    int t = (threadIdx.x >= o) ? sm[threadIdx.x - o] : 0;
    __syncthreads();
    sm[threadIdx.x] += t;
    __syncthreads();
  }
  if (i < n_nodes) rs[i] = sm[threadIdx.x] - v;  // exclusive
  if (threadIdx.x == SCAN_B - 1) partials[blockIdx.x] = sm[threadIdx.x];
}

__global__ __launch_bounds__(SCAN_B) void scan2_kernel(int* __restrict__ partials, int nb) {
  __shared__ int sm[SCAN_B];
  int v = (threadIdx.x < nb) ? partials[threadIdx.x] : 0;
  sm[threadIdx.x] = v;
  __syncthreads();
  for (int o = 1; o < SCAN_B; o <<= 1) {
    int t = (threadIdx.x >= o) ? sm[threadIdx.x - o] : 0;
    __syncthreads();
    sm[threadIdx.x] += t;
    __syncthreads();
  }
  if (threadIdx.x < nb) partials[threadIdx.x] = sm[threadIdx.x] - v;  // exclusive
}

__global__ __launch_bounds__(SCAN_B) void scan3_kernel(int* __restrict__ rs,
    const int* __restrict__ partials, int n_nodes) {
  int i = blockIdx.x * SCAN_B + threadIdx.x;
  if (i < n_nodes) rs[i] += partials[blockIdx.x];
}

// ---------------- CSR fill: rs is mutated to end-offsets ----------------
__global__ void fill_kernel(const int* __restrict__ src, const int* __restrict__ dst,
    int* __restrict__ rs, int* __restrict__ csr_eid, int* __restrict__ csr_src, int n_edges) {
  int e = blockIdx.x * blockDim.x + threadIdx.x;
  if (e >= n_edges) return;
  int d = dst[e];
  int pos = atomicAdd(&rs[d], 1);
  csr_eid[pos] = e;
  csr_src[pos] = src[e];
}

__global__ void dinva_kernel(const int* __restrict__ deg, float* __restrict__ dinv, int n_nodes) {
  int i = blockIdx.x * blockDim.x + threadIdx.x;
  if (i < n_nodes) dinv[i] = rsqrtf((float)deg[i] + 1.0f);
}

// ---------------- action layer1 gather + relu + project to xw2 [N,4] ----------------
__global__ __launch_bounds__(256) void agg1_kernel(const int* __restrict__ rs,
    const int* __restrict__ deg, const int* __restrict__ csr_src,
    const float* __restrict__ xw_a, const float* __restrict__ dinva,
    const float* __restrict__ ia1_b, const float* __restrict__ oa1_b,
    const float* __restrict__ ia2_w, const float* __restrict__ oa2_w,
    float* __restrict__ xw2_a, int n_nodes) {
  int t = blockIdx.x * blockDim.x + threadIdx.x;
  int node = t >> 5, j = t & 31;
  if (node >= n_nodes) return;
  int dg = deg[node];
  int st = rs[node] - dg;  // rs holds end offsets after fill
  float acc = 0.f;
  for (int i = 0; i < dg; ++i) {
    int s = csr_src[st + i];
    acc = fmaf(xw_a[(size_t)s * 32 + j], dinva[s], acc);
  }
  float di = dinva[node];
  float bias = (j < 16) ? ia1_b[j] : oa1_b[j - 16];
  float h = fmaxf(acc * di + xw_a[(size_t)node * 32 + j] * di * di + bias, 0.f);
  float w0 = (j < 16) ? ia2_w[j * 2 + 0] : oa2_w[(j - 16) * 2 + 0];
  float w1 = (j < 16) ? ia2_w[j * 2 + 1] : oa2_w[(j - 16) * 2 + 1];
  float p0 = h * w0, p1 = h * w1;
  #pragma unroll
  for (int o = 1; o < 16; o <<= 1) { p0 += __shfl_xor(p0, o); p1 += __shfl_xor(p1, o); }
  if ((j & 15) == 0) {
    int k = j >> 4;  // 0=in, 1=out
    xw2_a[(size_t)node * 4 + k * 2 + 0] = p0;
    xw2_a[(size_t)node * 4 + k * 2 + 1] = p1;
  }
}

// ---------------- action layer2 gather + gumbel flags (16 lanes/node) ----------------
__global__ void agg2_kernel(const int* __restrict__ rs, const int* __restrict__ deg,
    const int* __restrict__ csr_src, const float* __restrict__ xw2_a,
    const float* __restrict__ dinva, const float* __restrict__ ia2_b,
    const float* __restrict__ oa2_b, const float* __restrict__ u_in,
    const float* __restrict__ u_out, float* __restrict__ fin, float* __restrict__ fout,
    int n_nodes) {
  int t = blockIdx.x * blockDim.x + threadIdx.x;
  int node = t >> 4, l = t & 15;
  if (node >= n_nodes) return;
  int dg = deg[node];
  int st = rs[node] - dg;
  float a0 = 0.f, a1 = 0.f, a2 = 0.f, a3 = 0.f;
  for (int i = l; i < dg; i += 16) {
    int s = csr_src[st + i];
    float ds = dinva[s];
    float4 v = *(const float4*)&xw2_a[(size_t)s * 4];
    a0 = fmaf(v.x, ds, a0); a1 = fmaf(v.y, ds, a1);
    a2 = fmaf(v.z, ds, a2); a3 = fmaf(v.w, ds, a3);
  }
  #pragma unroll
  for (int o = 1; o < 16; o <<= 1) {
    a0 += __shfl_xor(a0, o); a1 += __shfl_xor(a1, o);
    a2 += __shfl_xor(a2, o); a3 += __shfl_xor(a3, o);
  }
  if (l == 0) {
    float di = dinva[node], sw = di * di;
    float4 self = *(const float4*)&xw2_a[(size_t)node * 4];
    float li0 = a0 * di + self.x * sw + ia2_b[0];
    float li1 = a1 * di + self.y * sw + ia2_b[1];
    float lo0 = a2 * di + self.z * sw + oa2_b[0];
    float lo1 = a3 * di + self.w * sw + oa2_b[1];
    float gi0 = -logf(-logf(u_in[(size_t)node * 2 + 0] + 1e-10f) + 1e-10f);
    float gi1 = -logf(-logf(u_in[(size_t)node * 2 + 1] + 1e-10f) + 1e-10f);
    float go0 = -logf(-logf(u_out[(size_t)node * 2 + 0] + 1e-10f) + 1e-10f);
    float go1 = -logf(-logf(u_out[(size_t)node * 2 + 1] + 1e-10f) + 1e-10f);
    fin[node]  = (li0 + gi0 >= li1 + gi1) ? 1.f : 0.f;
    fout[node] = (lo0 + go0 >= lo1 + go1) ? 1.f : 0.f;
  }
}

// ---------------- gated degree for final conv (16 lanes/node) ----------------
__global__ void cdeg_kernel(const int* __restrict__ rs, const int* __restrict__ deg,
    const int* __restrict__ csr_src, const float* __restrict__ fin,
    const float* __restrict__ fout, float* __restrict__ dinvc, int n_nodes) {
  int t = blockIdx.x * blockDim.x + threadIdx.x;
  int node = t >> 4, l = t & 15;
  if (node >= n_nodes) return;
  int dg = deg[node];
  int st = rs[node] - dg;
  float c = 0.f;
  if (fin[node] != 0.f) {
    for (int i = l; i < dg; i += 16) c += (fout[csr_src[st + i]] != 0.f) ? 1.f : 0.f;
  }
  #pragma unroll
  for (int o = 1; o < 16; o <<= 1) c += __shfl_xor(c, o);
  if (l == 0) dinvc[node] = rsqrtf(c + 1.0f);
}

// ---------------- xwc = xn @ conv_w (fp32, W staged in LDS) ----------------
#define GEMM_ROWS 64
__global__ __launch_bounds__(256) void gemm_kernel(const float* __restrict__ xn,
    const float* __restrict__ W, float* __restrict__ xwc, int n_nodes) {
  __shared__ __align__(16) float wl[DD * DD];  // 64 KB
  for (int i = threadIdx.x * 4; i < DD * DD; i += 256 * 4)
    *(float4*)&wl[i] = *(const float4*)&W[i];
  __syncthreads();
  int c4 = (threadIdx.x & 31) * 4;
  int r0 = threadIdx.x >> 5;
  int base = blockIdx.x * GEMM_ROWS;
  for (int r = r0; r < GEMM_ROWS; r += 8) {
    int n = base + r;
    if (n >= n_nodes) break;
    const float* xr = xn + (size_t)n * DD;
    float4 acc = {0.f, 0.f, 0.f, 0.f};
    #pragma unroll 4
    for (int d = 0; d < DD; ++d) {
      float xv = xr[d];
      float4 w = *(const float4*)&wl[d * DD + c4];
      acc.x = fmaf(xv, w.x, acc.x);
      acc.y = fmaf(xv, w.y, acc.y);
      acc.z = fmaf(xv, w.z, acc.z);
      acc.w = fmaf(xv, w.w, acc.w);
    }
    *(float4*)&xwc[(size_t)n * DD + c4] = acc;
  }
}

// ---------------- fused: per-block MFMA edge MLP into LDS + segment reduce ----------------
// Block covers CSR positions [P, P+EPB). Phase A: MLP (16->128, relu) via
// mfma_f32_16x16x32_bf16 (K zero-padded) into vt LDS tile. Phase B: walk the
// dst-sorted node segments; accumulate vt + gated conv gather; store (owned
// segments) or atomicAdd (boundary) into pre-zeroed out_acc.
__global__ __launch_bounds__(256) void edgenode_kernel(
    const int* __restrict__ rs, const int* __restrict__ deg,
    const int* __restrict__ csr_src, const int* __restrict__ csr_eid,
    const float* __restrict__ ea, const float* __restrict__ ep_w,
    const float* __restrict__ ep_b, const float* __restrict__ xwc,
    const float* __restrict__ dinvc, const float* __restrict__ fin,
    const float* __restrict__ fout, float* __restrict__ out_acc,
    int n_nodes, int n_edges) {
  __shared__ __align__(16) __bf16 vt[EPB * VT_STRIDE];  // ~67.6 KB
  __shared__ float comb[2][DD];
  const int tid = threadIdx.x;
  const int P = blockIdx.x * EPB;
  const int Pend = min(P + EPB, n_edges);

  // ---- phase A ----
  {
    const int l = tid & 63;
    const int w = tid >> 6;
    const int col = l & 15;
    const int kg = l >> 4;
    const int k0 = kg * 8;
    bf16x8 bfr[8];
    float bias[8];
    #pragma unroll
    for (int nt = 0; nt < 8; ++nt) {
      int j = nt * 16 + col;
      bf16x8 bb = {};
      if (k0 < HH) {
        #pragma unroll
        for (int i = 0; i < 8; ++i) bb[i] = (__bf16)ep_w[(k0 + i) * DD + j];
      }
      bfr[nt] = bb;
      bias[nt] = ep_b[j];
    }
    #pragma unroll
    for (int t = 0; t < 4; ++t) {
      int tile = w * 4 + t;
      int pos0 = P + tile * 16;
      if (pos0 < n_edges) {
        int apos = pos0 + col;
        int eid = csr_eid[(apos < n_edges) ? apos : (n_edges - 1)];
        bf16x8 afr = {};
        if (k0 < HH) {
          const float4* er = (const float4*)(ea + (size_t)eid * HH + k0);
          float4 f0 = er[0], f1 = er[1];
          afr[0] = (__bf16)f0.x; afr[1] = (__bf16)f0.y;
          afr[2] = (__bf16)f0.z; afr[3] = (__bf16)f0.w;
          afr[4] = (__bf16)f1.x; afr[5] = (__bf16)f1.y;
          afr[6] = (__bf16)f1.z; afr[7] = (__bf16)f1.w;
        }
        #pragma unroll
        for (int nt = 0; nt < 8; ++nt) {
          f32x4 d4 = {0.f, 0.f, 0.f, 0.f};
          d4 = __builtin_amdgcn_mfma_f32_16x16x32_bf16(afr, bfr[nt], d4, 0, 0, 0);
          #pragma unroll
          for (int r = 0; r < 4; ++r) {
            int rowl = tile * 16 + kg * 4 + r;  // D row = (lane>>4)*4 + r
            vt[rowl * VT_STRIDE + nt * 16 + col] = (__bf16)fmaxf(d4[r] + bias[nt], 0.f);
          }
        }
      }
    }
  }
  __syncthreads();

  // ---- phase B ----
  const int j = tid & 127;
  const int h = tid >> 7;
  // smallest d with rs[d] > P
  int lo = 0, hi = n_nodes;
  while (lo < hi) {
    int mid = (lo + hi) >> 1;
    if (rs[mid] > P) hi = mid; else lo = mid + 1;
  }
  int d = lo;
  int p = P;
  int seg = 0;
  while (p < Pend) {
    int re = rs[d];
    if (re <= p) { ++d; continue; }
    int se = (re < Pend) ? re : Pend;
    float fd = fin[d] * dinvc[d];
    float sum = 0.f;
    int pstart = p + (((p & 1) == h) ? 0 : 1);
    if (fd != 0.f) {
      for (int p2 = pstart; p2 < se; p2 += 2) {
        sum += (float)vt[(p2 - P) * VT_STRIDE + j];
        int s = csr_src[p2];
        float fs = fout[s];
        if (fs != 0.f) sum = fmaf(fd * dinvc[s], xwc[(size_t)s * DD + j], sum);
      }
    } else {
      for (int p2 = pstart; p2 < se; p2 += 2)
        sum += (float)vt[(p2 - P) * VT_STRIDE + j];
    }
    int k = seg & 1;
    if (h == 1) comb[k][j] = sum;
    __syncthreads();
    if (h == 0) {
      float total = sum + comb[k][j];
      bool full = (se == re) && (p == re - deg[d]);
      if (full) out_acc[(size_t)d * DD + j] = total;
      else atomicAdd(&out_acc[(size_t)d * DD + j], total);
    }
    p = se;
    if (se == re) ++d;
    ++seg;
  }
}

// ---------------- finalize: out = relu(acc + xwc*dinvc^2 + conv_b) ----------------
__global__ void final_kernel(float* __restrict__ out_acc, const float* __restrict__ xwc,
    const float* __restrict__ dinvc, const float* __restrict__ conv_b, int n_nodes) {
  int t = blockIdx.x * blockDim.x + threadIdx.x;
  if (t >= n_nodes * DD) return;
  int n = t >> 7, j = t & 127;
  float di = dinvc[n];
  float v = out_acc[t] + xwc[t] * di * di + conv_b[j];
  out_acc[t] = fmaxf(v, 0.f);
}

extern "C" void kernel_launch(void* const* d_in, const int* in_sizes, int n_in,
                              void* d_out, int out_size, void* d_ws, size_t ws_size,
                              hipStream_t stream) {
  const float* x      = (const float*)d_in[0];
  const int*   eidx   = (const int*)d_in[1];
  const float* ea     = (const float*)d_in[2];
  const float* u_in   = (const float*)d_in[3];
  const float* u_out  = (const float*)d_in[4];
  const float* ln_g   = (const float*)d_in[5];
  const float* ln_b   = (const float*)d_in[6];
  const float* conv_w = (const float*)d_in[7];
  const float* conv_b = (const float*)d_in[8];
  const float* ep_w   = (const float*)d_in[9];
  const float* ep_b   = (const float*)d_in[10];
  const float* ia1_w  = (const float*)d_in[11];
  const float* ia1_b  = (const float*)d_in[12];
  const float* ia2_w  = (const float*)d_in[13];
  const float* ia2_b  = (const float*)d_in[14];
  const float* oa1_w  = (const float*)d_in[15];
  const float* oa1_b  = (const float*)d_in[16];
  const float* oa2_w  = (const float*)d_in[17];
  const float* oa2_b  = (const float*)d_in[18];

  const int n = in_sizes[0] / DD;
  const int E = in_sizes[1] / 2;
  const int* src = eidx;
  const int* dst = eidx + E;

  float* ws = (float*)d_ws;
  float* xn    = ws;                            // 128n
  float* xw_a  = xn + (size_t)n * 128;          // 32n (aliased later by fin/fout/dinvc)
  float* xw2_a = xw_a + (size_t)n * 32;         // 4n
  float* dinva = xw2_a + (size_t)n * 4;         // n
  float* xwc   = dinva + n;                     // 128n
  int* deg_i   = (int*)(xwc + (size_t)n * 128); // n (zeroed)
  int* rs      = deg_i + n;                     // n
  int* partials= rs + n;                        // 1024
  int* csr_eid = partials + 1024;               // E
  int* csr_src = csr_eid + E;                   // E
  float* fin   = xw_a;                          // aliases, written after agg1 reads xw_a
  float* fout  = xw_a + n;
  float* dinvc = xw_a + 2 * (size_t)n;

  float* out_acc = (float*)d_out;

  hipMemsetAsync(deg_i, 0, (size_t)n * sizeof(int), stream);
  hipMemsetAsync(d_out, 0, (size_t)out_size * sizeof(float), stream);

  const int B = 256;
  const int nb = (n + SCAN_B - 1) / SCAN_B;

  ln_kernel<<<(n * 64 + B - 1) / B, B, 0, stream>>>(x, ln_g, ln_b, xn, n);
  proj1_kernel<<<(n * 32 + B - 1) / B, B, 0, stream>>>(xn, ia1_w, oa1_w, xw_a, n);
  degcnt_kernel<<<(E + B - 1) / B, B, 0, stream>>>(dst, deg_i, E);
  scan1_kernel<<<nb, SCAN_B, 0, stream>>>(deg_i, rs, partials, n);
  scan2_kernel<<<1, SCAN_B, 0, stream>>>(partials, nb);
  scan3_kernel<<<nb, SCAN_B, 0, stream>>>(rs, partials, n);
  dinva_kernel<<<(n + B - 1) / B, B, 0, stream>>>(deg_i, dinva, n);
  fill_kernel<<<(E + B - 1) / B, B, 0, stream>>>(src, dst, rs, csr_eid, csr_src, E);
  // after fill: rs[d] == end offset; start = rs[d] - deg[d]
  agg1_kernel<<<(n * 32 + B - 1) / B, B, 0, stream>>>(rs, deg_i, csr_src, xw_a, dinva,
                                                      ia1_b, oa1_b, ia2_w, oa2_w, xw2_a, n);
  agg2_kernel<<<(n * 16 + B - 1) / B, B, 0, stream>>>(rs, deg_i, csr_src, xw2_a, dinva,
                                                      ia2_b, oa2_b, u_in, u_out, fin, fout, n);
  cdeg_kernel<<<(n * 16 + B - 1) / B, B, 0, stream>>>(rs, deg_i, csr_src, fin, fout, dinvc, n);
  gemm_kernel<<<(n + GEMM_ROWS - 1) / GEMM_ROWS, B, 0, stream>>>(xn, conv_w, xwc, n);
  edgenode_kernel<<<(E + EPB - 1) / EPB, B, 0, stream>>>(rs, deg_i, csr_src, csr_eid,
      ea, ep_w, ep_b, xwc, dinvc, fin, fout, out_acc, n, E);
  final_kernel<<<((size_t)n * DD + B - 1) / B, B, 0, stream>>>(out_acc, xwc, dinvc, conv_b, n);
}

// Round 5
// 645.506 us; speedup vs baseline: 1.2179x; 1.2179x over previous
//
#include <hip/hip_runtime.h>
#include <hip/hip_bf16.h>

#define DD 128
#define HH 16
#define SCAN_B 1024
#define EPB 128        // CSR positions per block in edgenode_kernel
#define VT_STRIDE 132  // padded row stride (bf16) for vt tile

typedef __bf16 bf16x8 __attribute__((ext_vector_type(8)));
typedef float f32x4 __attribute__((ext_vector_type(4)));

// ---------------- LayerNorm: one wave per node ----------------
__global__ void ln_kernel(const float* __restrict__ x, const float* __restrict__ g,
                          const float* __restrict__ b, float* __restrict__ xn, int n_nodes) {
  int w = (blockIdx.x * blockDim.x + threadIdx.x) >> 6;
  int lane = threadIdx.x & 63;
  if (w >= n_nodes) return;
  const float* xr = x + (size_t)w * DD;
  float a0 = xr[lane], a1 = xr[lane + 64];
  float s = a0 + a1;
  #pragma unroll
  for (int o = 32; o > 0; o >>= 1) s += __shfl_down(s, o);
  s = __shfl(s, 0);
  float mu = s * (1.0f / DD);
  float d0 = a0 - mu, d1 = a1 - mu;
  float v = d0 * d0 + d1 * d1;
  #pragma unroll
  for (int o = 32; o > 0; o >>= 1) v += __shfl_down(v, o);
  v = __shfl(v, 0);
  float rstd = rsqrtf(v * (1.0f / DD) + 1e-5f);
  float* xo = xn + (size_t)w * DD;
  xo[lane]      = d0 * rstd * g[lane] + b[lane];
  xo[lane + 64] = d1 * rstd * g[lane + 64] + b[lane + 64];
}

// ---------------- xn @ [ia1_w | oa1_w] -> xw_a [N,32] ----------------
__global__ __launch_bounds__(256) void proj1_kernel(const float* __restrict__ xn,
    const float* __restrict__ ia1_w, const float* __restrict__ oa1_w,
    float* __restrict__ xw_a, int n_nodes) {
  __shared__ __align__(16) float wl[DD * 32];
  for (int i = threadIdx.x; i < DD * HH; i += 256) {
    int dd = i >> 4, jj = i & 15;
    wl[dd * 32 + jj]      = ia1_w[i];
    wl[dd * 32 + 16 + jj] = oa1_w[i];
  }
  __syncthreads();
  int t = blockIdx.x * blockDim.x + threadIdx.x;
  int n = t >> 5, j = t & 31;
  if (n >= n_nodes) return;
  const float* xr = xn + (size_t)n * DD;
  float acc = 0.f;
  #pragma unroll 8
  for (int d = 0; d < DD; ++d) acc = fmaf(xr[d], wl[d * 32 + j], acc);
  xw_a[(size_t)n * 32 + j] = acc;
}

// ---------------- degree histogram (int) ----------------
__global__ void degcnt_kernel(const int* __restrict__ dst, int* __restrict__ deg, int n_edges) {
  int e = blockIdx.x * blockDim.x + threadIdx.x;
  if (e < n_edges) atomicAdd(&deg[dst[e]], 1);
}

// ---------------- 3-kernel exclusive scan over deg -> rs ----------------
__global__ __launch_bounds__(SCAN_B) void scan1_kernel(const int* __restrict__ deg,
    int* __restrict__ rs, int* __restrict__ partials, int n_nodes) {
  __shared__ int sm[SCAN_B];
  int i = blockIdx.x * SCAN_B + threadIdx.x;
  int v = (i < n_nodes) ? deg[i] : 0;
  sm[threadIdx.x] = v;
  __syncthreads();
  for (int o = 1; o < SCAN_B; o <<= 1) {
    int t = (threadIdx.x >= o) ? sm[threadIdx.x - o] : 0;
    __syncthreads();
    sm[threadIdx.x] += t;
    __syncthreads();
  }
  if (i < n_nodes) rs[i] = sm[threadIdx.x] - v;  // exclusive
  if (threadIdx.x == SCAN_B - 1) partials[blockIdx.x] = sm[threadIdx.x];
}

__global__ __launch_bounds__(SCAN_B) void scan2_kernel(int* __restrict__ partials, int nb) {
  __shared__ int sm[SCAN_B];
  int v = (threadIdx.x < nb) ? partials[threadIdx.x] : 0;
  sm[threadIdx.x] = v;
  __syncthreads();
  for (int o = 1; o < SCAN_B; o <<= 1) {
    int t = (threadIdx.x >= o) ? sm[threadIdx.x - o] : 0;
    __syncthreads();
    sm[threadIdx.x] += t;
    __syncthreads();
  }
  if (threadIdx.x < nb) partials[threadIdx.x] = sm[threadIdx.x] - v;  // exclusive
}

// scan3 + dinva fused
__global__ __launch_bounds__(SCAN_B) void scan3_kernel(int* __restrict__ rs,
    const int* __restrict__ partials, const int* __restrict__ deg,
    float* __restrict__ dinva, int n_nodes) {
  int i = blockIdx.x * SCAN_B + threadIdx.x;
  if (i < n_nodes) {
    rs[i] += partials[blockIdx.x];
    dinva[i] = rsqrtf((float)deg[i] + 1.0f);
  }
}

// ---------------- CSR fill: rs is mutated to end-offsets ----------------
__global__ void fill_kernel(const int* __restrict__ src, const int* __restrict__ dst,
    int* __restrict__ rs, int* __restrict__ csr_eid, int* __restrict__ csr_src, int n_edges) {
  int e = blockIdx.x * blockDim.x + threadIdx.x;
  if (e >= n_edges) return;
  int d = dst[e];
  int pos = atomicAdd(&rs[d], 1);
  csr_eid[pos] = e;
  csr_src[pos] = src[e];
}

// ---------------- action layer1 gather + relu + project to xw2 [N,4] ----------------
__global__ __launch_bounds__(256) void agg1_kernel(const int* __restrict__ rs,
    const int* __restrict__ deg, const int* __restrict__ csr_src,
    const float* __restrict__ xw_a, const float* __restrict__ dinva,
    const float* __restrict__ ia1_b, const float* __restrict__ oa1_b,
    const float* __restrict__ ia2_w, const float* __restrict__ oa2_w,
    float* __restrict__ xw2_a, int n_nodes) {
  int t = blockIdx.x * blockDim.x + threadIdx.x;
  int node = t >> 5, j = t & 31;
  if (node >= n_nodes) return;
  int dg = deg[node];
  int st = rs[node] - dg;  // rs holds end offsets after fill
  float acc = 0.f;
  for (int i = 0; i < dg; ++i) {
    int s = csr_src[st + i];
    acc = fmaf(xw_a[(size_t)s * 32 + j], dinva[s], acc);
  }
  float di = dinva[node];
  float bias = (j < 16) ? ia1_b[j] : oa1_b[j - 16];
  float h = fmaxf(acc * di + xw_a[(size_t)node * 32 + j] * di * di + bias, 0.f);
  float w0 = (j < 16) ? ia2_w[j * 2 + 0] : oa2_w[(j - 16) * 2 + 0];
  float w1 = (j < 16) ? ia2_w[j * 2 + 1] : oa2_w[(j - 16) * 2 + 1];
  float p0 = h * w0, p1 = h * w1;
  #pragma unroll
  for (int o = 1; o < 16; o <<= 1) { p0 += __shfl_xor(p0, o); p1 += __shfl_xor(p1, o); }
  if ((j & 15) == 0) {
    int k = j >> 4;  // 0=in, 1=out
    xw2_a[(size_t)node * 4 + k * 2 + 0] = p0;
    xw2_a[(size_t)node * 4 + k * 2 + 1] = p1;
  }
}

// ---------------- action layer2 gather + gumbel flags (16 lanes/node) ----------------
__global__ void agg2_kernel(const int* __restrict__ rs, const int* __restrict__ deg,
    const int* __restrict__ csr_src, const float* __restrict__ xw2_a,
    const float* __restrict__ dinva, const float* __restrict__ ia2_b,
    const float* __restrict__ oa2_b, const float* __restrict__ u_in,
    const float* __restrict__ u_out, float* __restrict__ fin, float* __restrict__ fout,
    int n_nodes) {
  int t = blockIdx.x * blockDim.x + threadIdx.x;
  int node = t >> 4, l = t & 15;
  if (node >= n_nodes) return;
  int dg = deg[node];
  int st = rs[node] - dg;
  float a0 = 0.f, a1 = 0.f, a2 = 0.f, a3 = 0.f;
  for (int i = l; i < dg; i += 16) {
    int s = csr_src[st + i];
    float ds = dinva[s];
    float4 v = *(const float4*)&xw2_a[(size_t)s * 4];
    a0 = fmaf(v.x, ds, a0); a1 = fmaf(v.y, ds, a1);
    a2 = fmaf(v.z, ds, a2); a3 = fmaf(v.w, ds, a3);
  }
  #pragma unroll
  for (int o = 1; o < 16; o <<= 1) {
    a0 += __shfl_xor(a0, o); a1 += __shfl_xor(a1, o);
    a2 += __shfl_xor(a2, o); a3 += __shfl_xor(a3, o);
  }
  if (l == 0) {
    float di = dinva[node], sw = di * di;
    float4 self = *(const float4*)&xw2_a[(size_t)node * 4];
    float li0 = a0 * di + self.x * sw + ia2_b[0];
    float li1 = a1 * di + self.y * sw + ia2_b[1];
    float lo0 = a2 * di + self.z * sw + oa2_b[0];
    float lo1 = a3 * di + self.w * sw + oa2_b[1];
    float gi0 = -logf(-logf(u_in[(size_t)node * 2 + 0] + 1e-10f) + 1e-10f);
    float gi1 = -logf(-logf(u_in[(size_t)node * 2 + 1] + 1e-10f) + 1e-10f);
    float go0 = -logf(-logf(u_out[(size_t)node * 2 + 0] + 1e-10f) + 1e-10f);
    float go1 = -logf(-logf(u_out[(size_t)node * 2 + 1] + 1e-10f) + 1e-10f);
    fin[node]  = (li0 + gi0 >= li1 + gi1) ? 1.f : 0.f;
    fout[node] = (lo0 + go0 >= lo1 + go1) ? 1.f : 0.f;
  }
}

// ---------------- gated degree for final conv (16 lanes/node) ----------------
__global__ void cdeg_kernel(const int* __restrict__ rs, const int* __restrict__ deg,
    const int* __restrict__ csr_src, const float* __restrict__ fin,
    const float* __restrict__ fout, float* __restrict__ dinvc, int n_nodes) {
  int t = blockIdx.x * blockDim.x + threadIdx.x;
  int node = t >> 4, l = t & 15;
  if (node >= n_nodes) return;
  int dg = deg[node];
  int st = rs[node] - dg;
  float c = 0.f;
  if (fin[node] != 0.f) {
    for (int i = l; i < dg; i += 16) c += (fout[csr_src[st + i]] != 0.f) ? 1.f : 0.f;
  }
  #pragma unroll
  for (int o = 1; o < 16; o <<= 1) c += __shfl_xor(c, o);
  if (l == 0) dinvc[node] = rsqrtf(c + 1.0f);
}

// ---------------- xwc = xn @ conv_w (fp32, W staged in LDS) ----------------
#define GEMM_ROWS 64
__global__ __launch_bounds__(256) void gemm_kernel(const float* __restrict__ xn,
    const float* __restrict__ W, float* __restrict__ xwc, int n_nodes) {
  __shared__ __align__(16) float wl[DD * DD];  // 64 KB
  for (int i = threadIdx.x * 4; i < DD * DD; i += 256 * 4)
    *(float4*)&wl[i] = *(const float4*)&W[i];
  __syncthreads();
  int c4 = (threadIdx.x & 31) * 4;
  int r0 = threadIdx.x >> 5;
  int base = blockIdx.x * GEMM_ROWS;
  for (int r = r0; r < GEMM_ROWS; r += 8) {
    int n = base + r;
    if (n >= n_nodes) break;
    const float* xr = xn + (size_t)n * DD;
    float4 acc = {0.f, 0.f, 0.f, 0.f};
    #pragma unroll 4
    for (int d = 0; d < DD; ++d) {
      float xv = xr[d];
      float4 w = *(const float4*)&wl[d * DD + c4];
      acc.x = fmaf(xv, w.x, acc.x);
      acc.y = fmaf(xv, w.y, acc.y);
      acc.z = fmaf(xv, w.z, acc.z);
      acc.w = fmaf(xv, w.w, acc.w);
    }
    *(float4*)&xwc[(size_t)n * DD + c4] = acc;
  }
}

// ---------------- fused: per-block MFMA edge MLP into LDS + barrier-free segment reduce ----------------
// Block covers CSR positions [P, P+EPB). Phase A: MLP (16->128, relu) via
// mfma_f32_16x16x32_bf16 into vt. Then build segment table (ballot prefix).
// Phase B: each wave processes whole segments round-robin, no barriers:
// lane l owns cols {2l, 2l+1}; store (owned segment) or atomicAdd (boundary).
__global__ __launch_bounds__(256) void edgenode_kernel(
    const int* __restrict__ rs, const int* __restrict__ deg,
    const int* __restrict__ csr_src, const int* __restrict__ csr_eid,
    const float* __restrict__ ea, const float* __restrict__ ep_w,
    const float* __restrict__ ep_b, const float* __restrict__ xwc,
    const float* __restrict__ dinvc, const float* __restrict__ fin,
    const float* __restrict__ fout, float* __restrict__ out_acc,
    int n_nodes, int n_edges) {
  __shared__ __align__(16) __bf16 vt[EPB * VT_STRIDE];  // 33.8 KB
  __shared__ int dpos[EPB];
  __shared__ int seg_start[EPB + 1];
  __shared__ int seg_d[EPB];
  __shared__ int wcnt[2];
  const int tid = threadIdx.x;
  const int P = blockIdx.x * EPB;
  const int Pend = min(P + EPB, n_edges);

  // ---- phase A: MFMA edge MLP into vt ----
  {
    const int l = tid & 63;
    const int w = tid >> 6;
    const int col = l & 15;
    const int kg = l >> 4;
    const int k0 = kg * 8;
    bf16x8 bfr[8];
    float bias[8];
    #pragma unroll
    for (int nt = 0; nt < 8; ++nt) {
      int j = nt * 16 + col;
      bf16x8 bb = {};
      if (k0 < HH) {
        #pragma unroll
        for (int i = 0; i < 8; ++i) bb[i] = (__bf16)ep_w[(k0 + i) * DD + j];
      }
      bfr[nt] = bb;
      bias[nt] = ep_b[j];
    }
    #pragma unroll
    for (int t = 0; t < 2; ++t) {
      int tile = w * 2 + t;
      int pos0 = P + tile * 16;
      if (pos0 < n_edges) {
        int apos = pos0 + col;
        int eid = csr_eid[(apos < n_edges) ? apos : (n_edges - 1)];
        bf16x8 afr = {};
        if (k0 < HH) {
          const float4* er = (const float4*)(ea + (size_t)eid * HH + k0);
          float4 f0 = er[0], f1 = er[1];
          afr[0] = (__bf16)f0.x; afr[1] = (__bf16)f0.y;
          afr[2] = (__bf16)f0.z; afr[3] = (__bf16)f0.w;
          afr[4] = (__bf16)f1.x; afr[5] = (__bf16)f1.y;
          afr[6] = (__bf16)f1.z; afr[7] = (__bf16)f1.w;
        }
        #pragma unroll
        for (int nt = 0; nt < 8; ++nt) {
          f32x4 d4 = {0.f, 0.f, 0.f, 0.f};
          d4 = __builtin_amdgcn_mfma_f32_16x16x32_bf16(afr, bfr[nt], d4, 0, 0, 0);
          #pragma unroll
          for (int r = 0; r < 4; ++r) {
            int rowl = tile * 16 + kg * 4 + r;  // D row = (lane>>4)*4 + r
            vt[rowl * VT_STRIDE + nt * 16 + col] = (__bf16)fmaxf(d4[r] + bias[nt], 0.f);
          }
        }
      }
    }
  }

  // ---- segment table: dpos via binary search, then ballot prefix ----
  if (tid < EPB) {
    int pos = P + tid;
    int d = -1;
    if (pos < n_edges) {
      int lo = 0, hi = n_nodes;
      while (lo < hi) {
        int mid = (lo + hi) >> 1;
        if (rs[mid] > pos) hi = mid; else lo = mid + 1;
      }
      d = lo;
    }
    dpos[tid] = d;
  }
  __syncthreads();

  bool flag = false;
  if (tid < EPB && (P + tid) < n_edges)
    flag = (tid == 0) || (dpos[tid] != dpos[tid - 1]);
  unsigned long long bm = 0;
  int pre = 0;
  if (tid < EPB) {
    bm = __ballot(flag);
    int lane = tid & 63;
    pre = __popcll(bm & ((1ull << lane) - 1));
    if (lane == 0) wcnt[tid >> 6] = __popcll(bm);
  }
  __syncthreads();
  int NSEG = wcnt[0] + wcnt[1];
  if (flag) {
    int idx = pre + ((tid >> 6) ? wcnt[0] : 0);
    seg_start[idx] = tid;
    seg_d[idx] = dpos[tid];
  }
  if (tid == 0) seg_start[NSEG] = Pend - P;
  __syncthreads();

  // ---- phase B: waves process segments round-robin, barrier-free ----
  const int wid = tid >> 6;
  const int l = tid & 63;
  for (int sg = wid; sg < NSEG; sg += 4) {
    int p0 = seg_start[sg];
    int p1 = seg_start[sg + 1];
    int d = seg_d[sg];
    float fd = fin[d] * dinvc[d];
    float s0 = 0.f, s1 = 0.f;
    if (fd != 0.f) {
      for (int p = p0; p < p1; ++p) {
        unsigned u = *(const unsigned*)&vt[p * VT_STRIDE + 2 * l];
        s0 += __uint_as_float(u << 16);
        s1 += __uint_as_float(u & 0xffff0000u);
        int s = csr_src[P + p];
        float fs = fout[s];
        if (fs != 0.f) {
          float2 w = *(const float2*)(xwc + (size_t)s * DD + 2 * l);
          float c = fd * dinvc[s];
          s0 = fmaf(w.x, c, s0);
          s1 = fmaf(w.y, c, s1);
        }
      }
    } else {
      for (int p = p0; p < p1; ++p) {
        unsigned u = *(const unsigned*)&vt[p * VT_STRIDE + 2 * l];
        s0 += __uint_as_float(u << 16);
        s1 += __uint_as_float(u & 0xffff0000u);
      }
    }
    int gend = rs[d];
    bool full = ((P + p0) == gend - deg[d]) && ((P + p1) == gend);
    if (full) {
      float2 res = {s0, s1};
      *(float2*)(out_acc + (size_t)d * DD + 2 * l) = res;
    } else {
      atomicAdd(&out_acc[(size_t)d * DD + 2 * l], s0);
      atomicAdd(&out_acc[(size_t)d * DD + 2 * l + 1], s1);
    }
  }
}

// ---------------- finalize: out = relu(acc + xwc*dinvc^2 + conv_b) ----------------
__global__ void final_kernel(float* __restrict__ out_acc, const float* __restrict__ xwc,
    const float* __restrict__ dinvc, const float* __restrict__ conv_b, int n_nodes) {
  int t = blockIdx.x * blockDim.x + threadIdx.x;
  if (t >= n_nodes * DD) return;
  int n = t >> 7, j = t & 127;
  float di = dinvc[n];
  float v = out_acc[t] + xwc[t] * di * di + conv_b[j];
  out_acc[t] = fmaxf(v, 0.f);
}

extern "C" void kernel_launch(void* const* d_in, const int* in_sizes, int n_in,
                              void* d_out, int out_size, void* d_ws, size_t ws_size,
                              hipStream_t stream) {
  const float* x      = (const float*)d_in[0];
  const int*   eidx   = (const int*)d_in[1];
  const float* ea     = (const float*)d_in[2];
  const float* u_in   = (const float*)d_in[3];
  const float* u_out  = (const float*)d_in[4];
  const float* ln_g   = (const float*)d_in[5];
  const float* ln_b   = (const float*)d_in[6];
  const float* conv_w = (const float*)d_in[7];
  const float* conv_b = (const float*)d_in[8];
  const float* ep_w   = (const float*)d_in[9];
  const float* ep_b   = (const float*)d_in[10];
  const float* ia1_w  = (const float*)d_in[11];
  const float* ia1_b  = (const float*)d_in[12];
  const float* ia2_w  = (const float*)d_in[13];
  const float* ia2_b  = (const float*)d_in[14];
  const float* oa1_w  = (const float*)d_in[15];
  const float* oa1_b  = (const float*)d_in[16];
  const float* oa2_w  = (const float*)d_in[17];
  const float* oa2_b  = (const float*)d_in[18];

  const int n = in_sizes[0] / DD;
  const int E = in_sizes[1] / 2;
  const int* src = eidx;
  const int* dst = eidx + E;

  float* ws = (float*)d_ws;
  float* xn    = ws;                            // 128n
  float* xw_a  = xn + (size_t)n * 128;          // 32n (aliased later by fin/fout/dinvc)
  float* xw2_a = xw_a + (size_t)n * 32;         // 4n
  float* dinva = xw2_a + (size_t)n * 4;         // n
  float* xwc   = dinva + n;                     // 128n
  int* deg_i   = (int*)(xwc + (size_t)n * 128); // n (zeroed)
  int* rs      = deg_i + n;                     // n
  int* partials= rs + n;                        // 1024
  int* csr_eid = partials + 1024;               // E
  int* csr_src = csr_eid + E;                   // E
  float* fin   = xw_a;                          // aliases, written after agg1 reads xw_a
  float* fout  = xw_a + n;
  float* dinvc = xw_a + 2 * (size_t)n;

  float* out_acc = (float*)d_out;

  hipMemsetAsync(deg_i, 0, (size_t)n * sizeof(int), stream);
  hipMemsetAsync(d_out, 0, (size_t)out_size * sizeof(float), stream);

  const int B = 256;
  const int nb = (n + SCAN_B - 1) / SCAN_B;

  ln_kernel<<<(n * 64 + B - 1) / B, B, 0, stream>>>(x, ln_g, ln_b, xn, n);
  proj1_kernel<<<(n * 32 + B - 1) / B, B, 0, stream>>>(xn, ia1_w, oa1_w, xw_a, n);
  degcnt_kernel<<<(E + B - 1) / B, B, 0, stream>>>(dst, deg_i, E);
  scan1_kernel<<<nb, SCAN_B, 0, stream>>>(deg_i, rs, partials, n);
  scan2_kernel<<<1, SCAN_B, 0, stream>>>(partials, nb);
  scan3_kernel<<<nb, SCAN_B, 0, stream>>>(rs, partials, deg_i, dinva, n);
  fill_kernel<<<(E + B - 1) / B, B, 0, stream>>>(src, dst, rs, csr_eid, csr_src, E);
  // after fill: rs[d] == end offset; start = rs[d] - deg[d]
  agg1_kernel<<<(n * 32 + B - 1) / B, B, 0, stream>>>(rs, deg_i, csr_src, xw_a, dinva,
                                                      ia1_b, oa1_b, ia2_w, oa2_w, xw2_a, n);
  agg2_kernel<<<(n * 16 + B - 1) / B, B, 0, stream>>>(rs, deg_i, csr_src, xw2_a, dinva,
                                                      ia2_b, oa2_b, u_in, u_out, fin, fout, n);
  cdeg_kernel<<<(n * 16 + B - 1) / B, B, 0, stream>>>(rs, deg_i, csr_src, fin, fout, dinvc, n);
  gemm_kernel<<<(n + GEMM_ROWS - 1) / GEMM_ROWS, B, 0, stream>>>(xn, conv_w, xwc, n);
  edgenode_kernel<<<(E + EPB - 1) / EPB, B, 0, stream>>>(rs, deg_i, csr_src, csr_eid,
      ea, ep_w, ep_b, xwc, dinvc, fin, fout, out_acc, n, E);
  final_kernel<<<((size_t)n * DD + B - 1) / B, B, 0, stream>>>(out_acc, xwc, dinvc, conv_b, n);
}